// Round 10
// baseline (115.447 us; speedup 1.0000x reference)
//
#include <hip/hip_runtime.h>

// VQ-VAE VectorQuantizer fwd. K=1024, E=64, N=T*B=65536.
// bf16-split MFMA argmin (gap<6e-6 flagged) -> fp64 exact re-resolve.
// Scores t = ||c||^2 - 2 x.c; codebook pre-scaled by -2, ||c||^2 in C-init.
// MFMA roles: A = codebook frag, B = x frag -> D(lane l, reg r) =
// score(code = t*16 + (l>>4)*4 + r, row = base + (l&15)).
// R10: R9's resident x-frags (64 VGPR) starved the load pipeline (VALUBusy
// 35%, ~90% stall: compiler serialized the 6 b-loads/tile into L2 round
// trips). x-frags are tile-invariant -> re-read from LDS per tile (frees 64
// regs); b-stream double-buffered with static even/odd names, issued one
// tile ahead. Also: prep_ee folded into k_pack/k_exact64; memset folded
// into k_pack. 5 dispatches total.

#define KC 1024
#define ED 64
#define NR 65536
#define NE (NR * ED)
#define GAP1 6e-6f

typedef __attribute__((ext_vector_type(8))) short short8;
typedef __attribute__((ext_vector_type(4))) float f32x4;

__device__ __forceinline__ unsigned short bf16rne(float f) {
    unsigned u = __builtin_bit_cast(unsigned, f);
    return (unsigned short)((u + 0x7fffu + ((u >> 16) & 1u)) >> 16);
}
__device__ __forceinline__ float bf16tof(unsigned short h) {
    return __builtin_bit_cast(float, (unsigned)h << 16);
}

// Pack codebook fragments (MFMA A-operand) + ee4p C-init + zero counts/flag.
// Per code tile t, chunks j of -2*c: [ch e0-31|ch e32-63|cl e0-31|cl e32-63|
// ch e0-31|ch e32-63], paired at MFMA with x chunks [xh0|xh1|xh0|xh1|xl0|xl1].
// cbp[(t*6+j)*64+l]; ee4p: reg r, lane l, tile t <-> code t*16+(l>>4)*4+r.
__global__ __launch_bounds__(256) void k_pack(const float* __restrict__ cb,
        short8* __restrict__ cbp, f32x4* __restrict__ ee4p,
        unsigned* __restrict__ counts, unsigned* __restrict__ flagcnt) {
    int u = blockIdx.x * 256 + threadIdx.x;
    if (u < 1024) counts[u] = 0u;
    if (u == 1024) *flagcnt = 0u;
    if (u < 64 * 6 * 64) {
        int t = u / 384, rem = u % 384, j = rem / 64, l = rem % 64;
        int code = t * 16 + (l & 15), g = l >> 4;
        const float* c = cb + (size_t)code * ED;
        short8 o;
#pragma unroll
        for (int r = 0; r < 8; ++r) {
            int k = j * 32 + g * 8 + r;
            int e; bool lo;
            if (j < 2)      { e = k;       lo = false; }
            else if (j < 4) { e = k - 64;  lo = true;  }
            else            { e = k - 128; lo = false; }
            float m2 = -2.f * c[e];
            unsigned short h = bf16rne(m2);
            o[r] = lo ? (short)bf16rne(m2 - bf16tof(h)) : (short)h;
        }
        cbp[u] = o;
    } else if (u < 64 * 6 * 64 + 64 * 64) {
        int v = u - 64 * 6 * 64;
        int t = v >> 6, l = v & 63, g = l >> 4;
        f32x4 o;
#pragma unroll
        for (int r = 0; r < 4; ++r) {
            const float4* c4 = (const float4*)(cb + (size_t)(t * 16 + g * 4 + r) * ED);
            float s0 = 0.f, s1 = 0.f, s2 = 0.f, s3 = 0.f;
#pragma unroll
            for (int i = 0; i < 16; ++i) {
                float4 c = c4[i];
                s0 = fmaf(c.x, c.x, s0); s1 = fmaf(c.y, c.y, s1);
                s2 = fmaf(c.z, c.z, s2); s3 = fmaf(c.w, c.w, s3);
            }
            o[r] = (s0 + s1) + (s2 + s3);
        }
        ee4p[v] = o;
    }
}

// 1024 blocks x 512 threads (8 waves). Block owns rows [bid*64, +64).
// Phase 1: convert x -> bf16 hi/lo short8 frags in LDS once.
// Phase 2: wave w scans code tiles [w*8, w*8+8); x frags re-read from LDS
// per tile (tile-invariant, keeps VGPR free for the b double-buffer);
// b-stream loaded one tile ahead with static even/odd names.
// Phase 3: intra-wave shfl merge over g-groups, cross-wave LDS merge
// (ascending w == ascending k -> first-min tie-break preserved).
__global__ __launch_bounds__(512) void k_argmin(
        const float* __restrict__ in, const short8* __restrict__ cbp,
        const f32x4* __restrict__ ee4p, int* __restrict__ idx,
        unsigned* __restrict__ flagcnt, unsigned* __restrict__ flaglist) {
    __shared__ short8 xs[16][64];                 // [rt*4+q][l], 16KB
    __shared__ float sb[8][4][16], sb2[8][4][16];
    __shared__ int   sk[8][4][16];

    const int tid = threadIdx.x;
    const int l = tid & 63;
    const int wid = tid >> 6;                     // 0..7
    const int g = l >> 4;
    const int col = l & 15;
    const int rowBase = blockIdx.x * 64;

    // Phase 1: thread (row=tid&63, oct=tid>>6) builds hi+lo short8 for
    // lane ll=(oct&3)*16+(row&15), chunk h=oct>>2, rowtile row>>4.
    {
        const int row = tid & 63;
        const int oct = tid >> 6;
        const int h = oct >> 2;
        const int ll = (oct & 3) * 16 + (row & 15);
        const int rt = row >> 4;
        short8 H, L;
#pragma unroll
        for (int j = 0; j < 8; ++j) {
            const float x = in[(size_t)(oct * 8 + j) * NR + rowBase + row];
            const unsigned short hb = bf16rne(x);
            H[j] = (short)hb;
            L[j] = (short)bf16rne(x - bf16tof(hb));
        }
        xs[rt * 4 + h][ll] = H;
        xs[rt * 4 + 2 + h][ll] = L;
    }
    __syncthreads();

    float best[4]  = {3.4e38f, 3.4e38f, 3.4e38f, 3.4e38f};
    float best2[4] = {3.4e38f, 3.4e38f, 3.4e38f, 3.4e38f};
    int bestk[4] = {0, 0, 0, 0};

    const int t0 = wid * 8;

#define LOADT(P, T) do { \
        const short8* bp_ = cbp + (size_t)(T) * 384 + l; \
        P##0 = bp_[0];   P##1 = bp_[64];  P##2 = bp_[128]; \
        P##3 = bp_[192]; P##4 = bp_[256]; P##5 = bp_[320]; \
        P##e = ee4p[(T) * 64 + l]; \
    } while (0)

#define COMPT(P, T) do { \
        _Pragma("unroll") \
        for (int rt_ = 0; rt_ < 4; ++rt_) { \
            const short8 x0_ = xs[rt_ * 4 + 0][l]; \
            const short8 x1_ = xs[rt_ * 4 + 1][l]; \
            const short8 x2_ = xs[rt_ * 4 + 2][l]; \
            const short8 x3_ = xs[rt_ * 4 + 3][l]; \
            f32x4 acc_ = P##e; \
            acc_ = __builtin_amdgcn_mfma_f32_16x16x32_bf16(P##0, x0_, acc_, 0, 0, 0); \
            acc_ = __builtin_amdgcn_mfma_f32_16x16x32_bf16(P##1, x1_, acc_, 0, 0, 0); \
            acc_ = __builtin_amdgcn_mfma_f32_16x16x32_bf16(P##2, x0_, acc_, 0, 0, 0); \
            acc_ = __builtin_amdgcn_mfma_f32_16x16x32_bf16(P##3, x1_, acc_, 0, 0, 0); \
            acc_ = __builtin_amdgcn_mfma_f32_16x16x32_bf16(P##4, x2_, acc_, 0, 0, 0); \
            acc_ = __builtin_amdgcn_mfma_f32_16x16x32_bf16(P##5, x3_, acc_, 0, 0, 0); \
            _Pragma("unroll") \
            for (int r_ = 0; r_ < 4; ++r_) { \
                const float v_ = acc_[r_]; \
                const int k_ = (T) * 16 + g * 4 + r_; \
                const bool c_ = v_ < best[rt_]; \
                best2[rt_] = c_ ? best[rt_] : fminf(best2[rt_], v_); \
                bestk[rt_] = c_ ? k_ : bestk[rt_]; \
                best[rt_]  = c_ ? v_ : best[rt_]; \
            } \
        } \
    } while (0)

    // Phase 2: software-pipelined scan, static even/odd buffers.
    short8 A0, A1, A2, A3, A4, A5; f32x4 Ae;
    short8 C0, C1, C2, C3, C4, C5; f32x4 Ce;
    LOADT(A, t0);
#pragma unroll
    for (int p = 0; p < 4; ++p) {
        const int te = t0 + 2 * p;
        LOADT(C, te + 1);
        COMPT(A, te);
        if (p < 3) LOADT(A, te + 2);
        COMPT(C, te + 1);
    }
#undef LOADT
#undef COMPT

    // Phase 3a: intra-wave merge over the 4 g-groups.
#pragma unroll
    for (int rt = 0; rt < 4; ++rt) {
        float b = best[rt], b2 = best2[rt]; int k = bestk[rt];
#pragma unroll
        for (int sh = 16; sh <= 32; sh <<= 1) {
            const float ob  = __shfl_xor(b, sh, 64);
            const float ob2 = __shfl_xor(b2, sh, 64);
            const int   ok  = __shfl_xor(k, sh, 64);
            if (ob < b || (ob == b && ok < k)) { b2 = fminf(b, ob2); k = ok; b = ob; }
            else b2 = fminf(b2, ob);
        }
        if (g == 0) { sb[wid][rt][col] = b; sb2[wid][rt][col] = b2; sk[wid][rt][col] = k; }
    }
    __syncthreads();

    // Phase 3b: wave 0 merges the 8 wave-partials (ascending w == asc k).
    if (wid == 0) {
        const int rt = l >> 4, c2 = l & 15;
        float b = sb[0][rt][c2], b2 = sb2[0][rt][c2]; int k = sk[0][rt][c2];
#pragma unroll
        for (int w = 1; w < 8; ++w) {
            const float ob = sb[w][rt][c2], ob2 = sb2[w][rt][c2];
            const int ok = sk[w][rt][c2];
            if (ob < b || (ob == b && ok < k)) { b2 = fminf(b, ob2); k = ok; b = ob; }
            else b2 = fminf(b2, ob);
        }
        const int row = rowBase + rt * 16 + c2;
        idx[row] = k;
        if (b2 - b < GAP1) {
            const unsigned p = atomicAdd(flagcnt, 1u);
            flaglist[p] = (unsigned)row;
        }
    }
}

// fp64 exact argmin for flagged rows; one wave per row; ||c||^2 inline.
__global__ __launch_bounds__(256) void k_exact64(
        const float* __restrict__ in, const float* __restrict__ cb,
        int* __restrict__ idx,
        const unsigned* __restrict__ flagcnt, const unsigned* __restrict__ flaglist) {
    const unsigned nf = *flagcnt;
    const int l = threadIdx.x & 63;
    const unsigned wave = blockIdx.x * 4u + (unsigned)(threadIdx.x >> 6);
    const unsigned nwave = gridDim.x * 4u;
    for (unsigned i = wave; i < nf; i += nwave) {
        const int row = (int)flaglist[i];
        float x[ED];
#pragma unroll
        for (int e = 0; e < ED; ++e) x[e] = in[(size_t)e * NR + row];
        double best = 1e300; int bestk = 0;
        for (int ci = 0; ci < 16; ++ci) {
            const int k = ci * 64 + l;              // ascending k per lane
            const float* c = cb + (size_t)k * ED;
            double s = 0.0, e2 = 0.0;
            for (int e = 0; e < ED; ++e) {
                const double cv = (double)c[e];
                e2 = fma(cv, cv, e2);
                s  = fma(cv, (double)x[e], s);
            }
            const double t = fma(-2.0, s, e2);
            if (t < best) { best = t; bestk = k; }
        }
        for (int sh = 1; sh < 64; sh <<= 1) {
            const double ob = __shfl_xor(best, sh, 64);
            const int   ok  = __shfl_xor(bestk, sh, 64);
            if (ob < best || (ob == best && ok < bestk)) { best = ob; bestk = ok; }
        }
        if (l == 0) idx[row] = bestk;
    }
}

// Element-parallel gather/write/SSE + histogram. SSE: per-wave shfl reduce
// -> LDS -> one plain store per block (pblk[bid]); NO global atomics.
__global__ __launch_bounds__(256) void k_output(
        const float* __restrict__ in, const float* __restrict__ cb,
        const int* __restrict__ idx, float* __restrict__ qout,
        unsigned* __restrict__ counts, double* __restrict__ pblk) {
    __shared__ double sred[4];
    const int gtid = blockIdx.x * 256 + threadIdx.x;
    const int n = gtid & (NR - 1);
    const int e0 = gtid >> 16;                      // 0..7
    const int k = idx[n];
    if (e0 == 0) atomicAdd(&counts[k], 1u);
    const float4* c4 = (const float4*)(cb + (size_t)k * ED + e0 * 8);
    const float4 q0 = c4[0], q1 = c4[1];
    float local = 0.f;
#pragma unroll
    for (int j = 0; j < 8; ++j) {
        const int e = e0 * 8 + j;
        const float q = (j < 4) ? ((const float*)&q0)[j] : ((const float*)&q1)[j - 4];
        const float xv = in[(size_t)e * NR + n];
        qout[(size_t)e * NR + n] = q;
        const float d = q - xv;
        local = fmaf(d, d, local);
    }
    double ld = (double)local;
#pragma unroll
    for (int off = 32; off > 0; off >>= 1) ld += __shfl_down(ld, off, 64);
    if ((threadIdx.x & 63) == 0) sred[threadIdx.x >> 6] = ld;
    __syncthreads();
    if (threadIdx.x == 0)
        pblk[blockIdx.x] = (sred[0] + sred[1]) + (sred[2] + sred[3]);
}

// Final: entropy from counts + SSE from 2048 per-block partials (fixed-order
// tree -> deterministic).
__global__ __launch_bounds__(1024) void k_final(const unsigned* __restrict__ counts,
        const double* __restrict__ pblk, float* __restrict__ out) {
    __shared__ double redE[16], redS[16];
    const int tid = threadIdx.x;
    const double p = (double)counts[tid] * (1.0 / 65536.0);
    double term = p * log(p + 1e-10);
    double s = pblk[tid] + pblk[tid + 1024];
#pragma unroll
    for (int off = 32; off > 0; off >>= 1) {
        term += __shfl_down(term, off, 64);
        s    += __shfl_down(s,    off, 64);
    }
    if ((tid & 63) == 0) { redE[tid >> 6] = term; redS[tid >> 6] = s; }
    __syncthreads();
    if (tid == 0) {
        double e = 0.0, ss = 0.0;
        for (int i = 0; i < 16; ++i) { e += redE[i]; ss += redS[i]; }
        out[1 + NE] = (float)exp(-e);                 // perplexity
        const double m = ss * (1.0 / 4194304.0);      // mean((q-x)^2)
        out[0] = (float)(1.25 * m);                   // (1+beta)*m
    }
}

extern "C" void kernel_launch(void* const* d_in, const int* in_sizes, int n_in,
                              void* d_out, int out_size, void* d_ws, size_t ws_size,
                              hipStream_t stream) {
    (void)in_sizes; (void)n_in; (void)out_size; (void)ws_size;
    const float* in = (const float*)d_in[0];
    const float* cb = (const float*)d_in[1];
    float* out = (float*)d_out;

    // ws layout (dword offsets), strictly disjoint:
    //  [0,1024) counts | [1024] flagcnt
    //  [4160,102464) cbp 24576 short8 | [102464,118848) ee4p 4096 f32x4
    //  [118848,184384) idx | [184384,249920) flaglist
    //  pblk (2048 f64) at byte 999680 (8B-aligned)
    unsigned* counts   = (unsigned*)d_ws;
    unsigned* flagcnt  = (unsigned*)d_ws + 1024;
    short8*   cbp      = (short8*)((float*)d_ws + 4160);
    f32x4*    ee4p     = (f32x4*)((float*)d_ws + 102464);
    int*      idx      = (int*)d_ws + 118848;
    unsigned* flaglist = (unsigned*)d_ws + 184384;
    double*   pblk     = (double*)((char*)d_ws + 999680);

    hipLaunchKernelGGL(k_pack,    dim3(112),  dim3(256),  0, stream,
                       cb, cbp, ee4p, counts, flagcnt);
    hipLaunchKernelGGL(k_argmin,  dim3(1024), dim3(512),  0, stream,
                       in, cbp, ee4p, idx, flagcnt, flaglist);
    hipLaunchKernelGGL(k_exact64, dim3(128),  dim3(256),  0, stream,
                       in, cb, idx, flagcnt, flaglist);
    hipLaunchKernelGGL(k_output,  dim3(2048), dim3(256),  0, stream,
                       in, cb, idx, out + 1, counts, pblk);
    hipLaunchKernelGGL(k_final,   dim3(1),    dim3(1024), 0, stream,
                       counts, pblk, out);
}

// Round 11
// 93.058 us; speedup vs baseline: 1.2406x; 1.2406x over previous
//
#include <hip/hip_runtime.h>

// VQ-VAE VectorQuantizer fwd. K=1024, E=64, N=T*B=65536.
// bf16-split MFMA argmin (gap<6e-6 flagged) -> fp64 exact re-resolve.
// Scores t = ||c||^2 - 2 x.c; codebook pre-scaled by -2, ||c||^2 in C-init.
// MFMA roles: A = codebook frag, B = x frag -> D(lane l, reg r) =
// score(code = t*16 + (l>>4)*4 + r, row = base + (l&15)).
// R11: L1-reuse restructure. R4-R10 K-split gave every wave a disjoint
// codebook stream -> 100% L1 miss -> per-CU miss queue saturation (VALUBusy
// stuck ~35% despite 24 resident waves). Now: 256 blocks x 1024 thr
// (4 row-groups x 4 K-quarters); the 4 waves of a K-quarter read the SAME
// 16-tile stream (L1 serves 3/4). x->LDS once (phase 1), per-wave frags in
// 64 VGPR (R9's proven-80-VGPR body). med3 min-track (4 VALU/score). Tile
// record packed contiguous: 6 frags + ||c||^2 = 7KB.

#define KC 1024
#define ED 64
#define NR 65536
#define NE (NR * ED)
#define GAP1 6e-6f

typedef __attribute__((ext_vector_type(8))) short short8;
typedef __attribute__((ext_vector_type(4))) float f32x4;

__device__ __forceinline__ unsigned short bf16rne(float f) {
    unsigned u = __builtin_bit_cast(unsigned, f);
    return (unsigned short)((u + 0x7fffu + ((u >> 16) & 1u)) >> 16);
}
__device__ __forceinline__ float bf16tof(unsigned short h) {
    return __builtin_bit_cast(float, (unsigned)h << 16);
}

// Pack tile records + zero counts/flag. Record t (7KB): j=0..5 codebook
// fragments of -2*c (chunks [ch e0-31|ch e32-63|cl e0-31|cl e32-63|ch e0-31|
// ch e32-63], paired at MFMA with x chunks [xh0|xh1|xh0|xh1|xl0|xl1]; elem
// (g=l>>4,r) <-> k-slot g*8+r, same bijection both operands); j=6: f32x4
// ||c||^2 C-init (reg r, lane l <-> code t*16+(l>>4)*4+r), bitcast short8.
__global__ __launch_bounds__(256) void k_pack(const float* __restrict__ cb,
        short8* __restrict__ cbt, unsigned* __restrict__ counts,
        unsigned* __restrict__ flagcnt) {
    const int u = blockIdx.x * 256 + threadIdx.x;
    if (u < 1024) counts[u] = 0u;
    if (u == 1024) *flagcnt = 0u;
    if (u >= 64 * 7 * 64) return;
    const int t = u / 448, rem = u % 448, j = rem / 64, l = rem % 64;
    const int g = l >> 4;
    if (j < 6) {
        const int code = t * 16 + (l & 15);
        const float* c = cb + (size_t)code * ED;
        short8 o;
#pragma unroll
        for (int r = 0; r < 8; ++r) {
            const int k = j * 32 + g * 8 + r;
            int e; bool lo;
            if (j < 2)      { e = k;       lo = false; }
            else if (j < 4) { e = k - 64;  lo = true;  }
            else            { e = k - 128; lo = false; }
            const float m2 = -2.f * c[e];
            const unsigned short h = bf16rne(m2);
            o[r] = lo ? (short)bf16rne(m2 - bf16tof(h)) : (short)h;
        }
        cbt[u] = o;
    } else {
        f32x4 o;
#pragma unroll
        for (int r = 0; r < 4; ++r) {
            const float4* c4 = (const float4*)(cb + (size_t)(t * 16 + g * 4 + r) * ED);
            float s0 = 0.f, s1 = 0.f, s2 = 0.f, s3 = 0.f;
#pragma unroll
            for (int i = 0; i < 16; ++i) {
                const float4 c = c4[i];
                s0 = fmaf(c.x, c.x, s0); s1 = fmaf(c.y, c.y, s1);
                s2 = fmaf(c.z, c.z, s2); s3 = fmaf(c.w, c.w, s3);
            }
            o[r] = (s0 + s1) + (s2 + s3);
        }
        cbt[u] = __builtin_bit_cast(short8, o);
    }
}

// 256 blocks x 1024 threads (16 waves = 4 row-groups x 4 K-quarters).
// Block owns 256 rows. Phase 1: all threads convert x -> bf16 hi/lo short8
// into LDS xs (once). Phase 2: wave (rg=wid>>2, kh=wid&3) loads its 16 x
// frags to regs, scans tiles [kh*16, kh*16+16); the 4 waves per kh share
// the tile stream (L1 reuse x4). Phase 3: shfl g-merge, LDS merge across
// kh (ascending kh == ascending k -> first-min tie-break).
__global__ __launch_bounds__(1024) void k_argmin(
        const float* __restrict__ in, const short8* __restrict__ cbt,
        int* __restrict__ idx, unsigned* __restrict__ flagcnt,
        unsigned* __restrict__ flaglist) {
    __shared__ short8 xs[4][16][64];              // 64 KB
    __shared__ float sb[16][4][16], sb2[16][4][16];
    __shared__ int   sk[16][4][16];

    const int tid = threadIdx.x;
    const int l = tid & 63;
    const int wid = tid >> 6;                     // 0..15
    const int g = l >> 4;
    const int col = l & 15;
    const int rowBase = blockIdx.x * 256;

    // Phase 1: thread (row=tid&255, ob=tid>>8) converts octs {ob, ob+4}
    // of its row; ll = (ob)*16 + (row&15), slot = rt*4 + h (+2 for lo).
    {
        const int row = tid & 255;
        const int ob = tid >> 8;                  // 0..3 == oct&3
        const int rg = row >> 6;
        const int r6 = row & 63;
        const int rt = r6 >> 4;
        const int ll = ob * 16 + (r6 & 15);
#pragma unroll
        for (int hh = 0; hh < 2; ++hh) {
            const int oct = ob + hh * 4;
            short8 H, L;
#pragma unroll
            for (int j = 0; j < 8; ++j) {
                const float x = in[(size_t)(oct * 8 + j) * NR + rowBase + row];
                const unsigned short hb = bf16rne(x);
                H[j] = (short)hb;
                L[j] = (short)bf16rne(x - bf16tof(hb));
            }
            xs[rg][rt * 4 + hh][ll] = H;
            xs[rg][rt * 4 + 2 + hh][ll] = L;
        }
    }
    __syncthreads();

    // Phase 2: x frags to regs (once), scan this K-quarter's 16 tiles.
    const int rg = wid >> 2, kh = wid & 3;
    short8 xq[4][4];
#pragma unroll
    for (int rt = 0; rt < 4; ++rt)
#pragma unroll
        for (int q = 0; q < 4; ++q)
            xq[rt][q] = xs[rg][rt * 4 + q][l];

    float best[4]  = {3.4e38f, 3.4e38f, 3.4e38f, 3.4e38f};
    float best2[4] = {3.4e38f, 3.4e38f, 3.4e38f, 3.4e38f};
    int bestk[4] = {0, 0, 0, 0};

#pragma unroll 2
    for (int tt = 0; tt < 16; ++tt) {
        const int t = kh * 16 + tt;
        const short8* bp = cbt + (size_t)t * 448 + l;
        const short8 b0 = bp[0], b1 = bp[64], b2 = bp[128],
                     b3 = bp[192], b4 = bp[256], b5 = bp[320];
        const f32x4 e4 = __builtin_bit_cast(f32x4, bp[384]);
#pragma unroll
        for (int rt = 0; rt < 4; ++rt) {
            f32x4 acc = e4;
            acc = __builtin_amdgcn_mfma_f32_16x16x32_bf16(b0, xq[rt][0], acc, 0, 0, 0);
            acc = __builtin_amdgcn_mfma_f32_16x16x32_bf16(b1, xq[rt][1], acc, 0, 0, 0);
            acc = __builtin_amdgcn_mfma_f32_16x16x32_bf16(b2, xq[rt][0], acc, 0, 0, 0);
            acc = __builtin_amdgcn_mfma_f32_16x16x32_bf16(b3, xq[rt][1], acc, 0, 0, 0);
            acc = __builtin_amdgcn_mfma_f32_16x16x32_bf16(b4, xq[rt][2], acc, 0, 0, 0);
            acc = __builtin_amdgcn_mfma_f32_16x16x32_bf16(b5, xq[rt][3], acc, 0, 0, 0);
#pragma unroll
            for (int r = 0; r < 4; ++r) {
                const float v = acc[r];
                const int k = t * 16 + g * 4 + r;
                best2[rt] = fminf(fmaxf(v, best[rt]), best2[rt]);  // med3
                const bool c = v < best[rt];                       // strict <
                bestk[rt] = c ? k : bestk[rt];
                best[rt]  = fminf(v, best[rt]);
            }
        }
    }

    // Phase 3a: intra-wave merge over the 4 g-groups.
#pragma unroll
    for (int rt = 0; rt < 4; ++rt) {
        float b = best[rt], b2 = best2[rt]; int k = bestk[rt];
#pragma unroll
        for (int sh = 16; sh <= 32; sh <<= 1) {
            const float ob  = __shfl_xor(b, sh, 64);
            const float ob2 = __shfl_xor(b2, sh, 64);
            const int   ok  = __shfl_xor(k, sh, 64);
            if (ob < b || (ob == b && ok < k)) { b2 = fminf(b, ob2); k = ok; b = ob; }
            else b2 = fminf(b2, ob);
        }
        if (g == 0) { sb[wid][rt][col] = b; sb2[wid][rt][col] = b2; sk[wid][rt][col] = k; }
    }
    __syncthreads();

    // Phase 3b: waves 0..3 merge rg=wid across its 4 kh slices (asc k).
    if (wid < 4) {
        const int rt = l >> 4, c2 = l & 15;
        float b = sb[wid * 4][rt][c2], b2 = sb2[wid * 4][rt][c2];
        int k = sk[wid * 4][rt][c2];
#pragma unroll
        for (int s = 1; s < 4; ++s) {
            const float ob = sb[wid * 4 + s][rt][c2], ob2 = sb2[wid * 4 + s][rt][c2];
            const int ok = sk[wid * 4 + s][rt][c2];
            if (ob < b || (ob == b && ok < k)) { b2 = fminf(b, ob2); k = ok; b = ob; }
            else b2 = fminf(b2, ob);
        }
        const int row = rowBase + wid * 64 + rt * 16 + c2;
        idx[row] = k;
        if (b2 - b < GAP1) {
            const unsigned p = atomicAdd(flagcnt, 1u);
            flaglist[p] = (unsigned)row;
        }
    }
}

// fp64 exact argmin for flagged rows; one wave per row; ||c||^2 inline.
__global__ __launch_bounds__(256) void k_exact64(
        const float* __restrict__ in, const float* __restrict__ cb,
        int* __restrict__ idx,
        const unsigned* __restrict__ flagcnt, const unsigned* __restrict__ flaglist) {
    const unsigned nf = *flagcnt;
    const int l = threadIdx.x & 63;
    const unsigned wave = blockIdx.x * 4u + (unsigned)(threadIdx.x >> 6);
    const unsigned nwave = gridDim.x * 4u;
    for (unsigned i = wave; i < nf; i += nwave) {
        const int row = (int)flaglist[i];
        float x[ED];
#pragma unroll
        for (int e = 0; e < ED; ++e) x[e] = in[(size_t)e * NR + row];
        double best = 1e300; int bestk = 0;
        for (int ci = 0; ci < 16; ++ci) {
            const int k = ci * 64 + l;              // ascending k per lane
            const float* c = cb + (size_t)k * ED;
            double s = 0.0, e2 = 0.0;
            for (int e = 0; e < ED; ++e) {
                const double cv = (double)c[e];
                e2 = fma(cv, cv, e2);
                s  = fma(cv, (double)x[e], s);
            }
            const double t = fma(-2.0, s, e2);
            if (t < best) { best = t; bestk = k; }
        }
        for (int sh = 1; sh < 64; sh <<= 1) {
            const double ob = __shfl_xor(best, sh, 64);
            const int   ok  = __shfl_xor(bestk, sh, 64);
            if (ob < best || (ob == best && ok < bestk)) { best = ob; bestk = ok; }
        }
        if (l == 0) idx[row] = bestk;
    }
}

// Element-parallel gather/write/SSE + histogram. SSE: per-wave shfl reduce
// -> LDS -> one plain store per block (pblk[bid]); NO global atomics.
__global__ __launch_bounds__(256) void k_output(
        const float* __restrict__ in, const float* __restrict__ cb,
        const int* __restrict__ idx, float* __restrict__ qout,
        unsigned* __restrict__ counts, double* __restrict__ pblk) {
    __shared__ double sred[4];
    const int gtid = blockIdx.x * 256 + threadIdx.x;
    const int n = gtid & (NR - 1);
    const int e0 = gtid >> 16;                      // 0..7
    const int k = idx[n];
    if (e0 == 0) atomicAdd(&counts[k], 1u);
    const float4* c4 = (const float4*)(cb + (size_t)k * ED + e0 * 8);
    const float4 q0 = c4[0], q1 = c4[1];
    float local = 0.f;
#pragma unroll
    for (int j = 0; j < 8; ++j) {
        const int e = e0 * 8 + j;
        const float q = (j < 4) ? ((const float*)&q0)[j] : ((const float*)&q1)[j - 4];
        const float xv = in[(size_t)e * NR + n];
        qout[(size_t)e * NR + n] = q;
        const float d = q - xv;
        local = fmaf(d, d, local);
    }
    double ld = (double)local;
#pragma unroll
    for (int off = 32; off > 0; off >>= 1) ld += __shfl_down(ld, off, 64);
    if ((threadIdx.x & 63) == 0) sred[threadIdx.x >> 6] = ld;
    __syncthreads();
    if (threadIdx.x == 0)
        pblk[blockIdx.x] = (sred[0] + sred[1]) + (sred[2] + sred[3]);
}

// Final: entropy from counts + SSE from 2048 per-block partials (fixed-order
// tree -> deterministic).
__global__ __launch_bounds__(1024) void k_final(const unsigned* __restrict__ counts,
        const double* __restrict__ pblk, float* __restrict__ out) {
    __shared__ double redE[16], redS[16];
    const int tid = threadIdx.x;
    const double p = (double)counts[tid] * (1.0 / 65536.0);
    double term = p * log(p + 1e-10);
    double s = pblk[tid] + pblk[tid + 1024];
#pragma unroll
    for (int off = 32; off > 0; off >>= 1) {
        term += __shfl_down(term, off, 64);
        s    += __shfl_down(s,    off, 64);
    }
    if ((tid & 63) == 0) { redE[tid >> 6] = term; redS[tid >> 6] = s; }
    __syncthreads();
    if (tid == 0) {
        double e = 0.0, ss = 0.0;
        for (int i = 0; i < 16; ++i) { e += redE[i]; ss += redS[i]; }
        out[1 + NE] = (float)exp(-e);                 // perplexity
        const double m = ss * (1.0 / 4194304.0);      // mean((q-x)^2)
        out[0] = (float)(1.25 * m);                   // (1+beta)*m
    }
}

extern "C" void kernel_launch(void* const* d_in, const int* in_sizes, int n_in,
                              void* d_out, int out_size, void* d_ws, size_t ws_size,
                              hipStream_t stream) {
    (void)in_sizes; (void)n_in; (void)out_size; (void)ws_size;
    const float* in = (const float*)d_in[0];
    const float* cb = (const float*)d_in[1];
    float* out = (float*)d_out;

    // ws layout (dword offsets), strictly disjoint:
    //  [0,1024) counts | [1024] flagcnt
    //  [4160,118848) cbt: 28672 short8 tile records (448 KB, 16B-aligned)
    //  [118848,184384) idx | [184384,249920) flaglist
    //  pblk (2048 f64) at byte 999680 (8B-aligned)
    unsigned* counts   = (unsigned*)d_ws;
    unsigned* flagcnt  = (unsigned*)d_ws + 1024;
    short8*   cbt      = (short8*)((float*)d_ws + 4160);
    int*      idx      = (int*)d_ws + 118848;
    unsigned* flaglist = (unsigned*)d_ws + 184384;
    double*   pblk     = (double*)((char*)d_ws + 999680);

    hipLaunchKernelGGL(k_pack,    dim3(112),  dim3(256),  0, stream,
                       cb, cbt, counts, flagcnt);
    hipLaunchKernelGGL(k_argmin,  dim3(256),  dim3(1024), 0, stream,
                       in, cbt, idx, flagcnt, flaglist);
    hipLaunchKernelGGL(k_exact64, dim3(128),  dim3(256),  0, stream,
                       in, cb, idx, flagcnt, flaglist);
    hipLaunchKernelGGL(k_output,  dim3(2048), dim3(256),  0, stream,
                       in, cb, idx, out + 1, counts, pblk);
    hipLaunchKernelGGL(k_final,   dim3(1),    dim3(1024), 0, stream,
                       counts, pblk, out);
}